// Round 18
// baseline (59.580 us; speedup 1.0000x reference)
//
#include <hip/hip_runtime.h>
#include <hip/hip_bf16.h>

// Fully-fused deform-conv MNIST net. B=2048, TWO images per block (512 thr).
// Per-image LDS = 20736 B (img2b overlays offbuf via register-staged phase B),
// total 41472 B -> 3 blocks/CU = 24 waves/CU potential.
// launch_bounds(512,2) -> 256-reg budget, no spill (r15 verified VGPR 52).
//   s5[img] : xs|img2bf (ph0-1) -> offbuf (phA..B-read) -> img2b (phB-write..C)
//   imgb[img]: bf16 ch-last h1 (ph2..B-read) -> pl+wred (phC-E)

#define B_IMG 2048

typedef short bf16x8 __attribute__((ext_vector_type(8)));
typedef float f32x4 __attribute__((ext_vector_type(4)));

// wqo  [5][32][32]  : off2_w (32,16,3,3) -> k=sl*16+ic, s=2*sp+sl, s>=9 zero
// wq2  [13][32][32] : conv2_w (32,16,5,5) -> s>=25 zero
// wqc1 [16][32]     : conv1_w (16,1,5,5)  -> k=tap, k>=25 zero
__global__ __launch_bounds__(256) void k_prep(const float* __restrict__ w_off2,
                                              const float* __restrict__ w_c2,
                                              const float* __restrict__ w_c1,
                                              __hip_bfloat16* __restrict__ wqo,
                                              __hip_bfloat16* __restrict__ wq2,
                                              __hip_bfloat16* __restrict__ wqc1) {
    int e = blockIdx.x * 256 + threadIdx.x;
    if (e < 5120) {
        int sp = e >> 10, rem = e & 1023, oc = rem >> 5, k = rem & 31;
        int sl = k >> 4, ic = k & 15, s = 2 * sp + sl;
        wqo[e] = __float2bfloat16(s < 9 ? w_off2[(oc * 16 + ic) * 9 + s] : 0.f);
    } else if (e < 18432) {
        int e2 = e - 5120;
        int sp = e2 >> 10, rem = e2 & 1023, oc = rem >> 5, k = rem & 31;
        int sl = k >> 4, ic = k & 15, s = 2 * sp + sl;
        wq2[e2] = __float2bfloat16(s < 25 ? w_c2[(oc * 16 + ic) * 25 + s] : 0.f);
    } else if (e < 18944) {
        int e3 = e - 18432;
        int oc = e3 >> 5, k = e3 & 31;
        wqc1[e3] = __float2bfloat16(k < 25 ? w_c1[oc * 25 + k] : 0.f);
    }
}

__global__ __launch_bounds__(512, 2) void k_net(const float* __restrict__ x,        // (B,1,28,28)
                                                const float* __restrict__ off1_w,   // (2,1,3,3)
                                                const __hip_bfloat16* __restrict__ wqc1,
                                                const float* __restrict__ conv1_b,  // (16)
                                                const __hip_bfloat16* __restrict__ wqo,
                                                const __hip_bfloat16* __restrict__ wq2,
                                                const float* __restrict__ conv2_b,  // (32)
                                                const float* __restrict__ fc_w,     // (10,1568)
                                                const float* __restrict__ fc_b,     // (10)
                                                float* __restrict__ out) {          // (B,10)
    __shared__ __align__(16) char s5[2][12544];                     // per-image scratch
    __shared__ __align__(16) __hip_bfloat16 imgb[2][16 * 16 * 16];  // per-image 8192 B

    int t0 = threadIdx.x;
    int img = t0 >> 8;   // 0 or 1
    int t = t0 & 255;    // per-image thread id
    int b = blockIdx.x * 2 + img;

    char* s5i = s5[img];
    float* xs = (float*)s5i;                                 // [30][30] pad1, 3600 B
    __hip_bfloat16* img2bf = (__hip_bfloat16*)(s5i + 3600);  // [32][36] pad2 bf16, 2304 B
    _Float16* offbuf = (_Float16*)s5i;                       // phA..B-read, 12544 B
    __hip_bfloat16* img2b = (__hip_bfloat16*)s5i;            // [18][20][16] phB-write..C
    __hip_bfloat16* imgbI = imgb[img];
    float* pl    = (float*)imgbI;                            // phase C-E, 6272 B
    float* wredp = (float*)((char*)imgbI + 6272);            // phase E, 160 B

    // ---- phase 0: prefetch x to regs, zero pads, then stage input ----
    float xreg[4];
#pragma unroll
    for (int j = 0; j < 4; ++j) {
        int i = t + j * 256;
        xreg[j] = (i < 784) ? x[b * 784 + i] : 0.f;  // HBM loads issued early
    }
    for (int i = t; i < 900; i += 256) xs[i] = 0.f;
    for (int i = t; i < 576; i += 256) ((unsigned int*)img2bf)[i] = 0u;
    // imgb: interior fully overwritten by phase 2 -> zero only pad cells (480 words)
    for (int i = t; i < 480; i += 256) {
        int word = i & 7;
        int cell = i >> 3;  // 0..59
        int row, col;
        if (cell < 16) { row = 0; col = cell; }
        else if (cell < 32) { row = 15; col = cell - 16; }
        else { int q = cell - 32; row = 1 + (q >> 1); col = (q & 1) * 15; }
        ((unsigned int*)imgbI)[(row * 16 + col) * 8 + word] = 0u;
    }
    __syncthreads();
#pragma unroll
    for (int j = 0; j < 4; ++j) {
        int i = t + j * 256;
        if (i < 784) xs[(i / 28 + 1) * 30 + (i % 28) + 1] = xreg[j];
    }
    __syncthreads();

    // ---- phase 1: deform1 -> img2bf (bf16, pad2, 36-wide); division-free ----
    {
        int h = t / 28, w = t % 28;  // one div; then incremental
        for (int p = t; p < 784; p += 256) {
            int c = (h >= 14) ? 1 : 0;
            int hp = h - 14 * c;
            const float* wo = off1_w + c * 9;
            float off[2];
#pragma unroll
            for (int k = 0; k < 2; ++k) {
                int e = 2 * w + k;
                int wrap = (e >= 28) ? 1 : 0;
                int hh = 2 * hp + wrap;
                int ww = e - 28 * wrap;
                float s = 0.f;
#pragma unroll
                for (int dy = 0; dy < 3; ++dy)
#pragma unroll
                    for (int dx = 0; dx < 3; ++dx)
                        s += wo[dy * 3 + dx] * xs[(hh + dy) * 30 + ww + dx];
                off[k] = s;
            }
            float cy = fminf(fmaxf((float)h + off[0], 0.f), 27.f);
            float cx = fminf(fmaxf((float)w + off[1], 0.f), 27.f);
            float y0f = floorf(cy), x0f = floorf(cx);
            int y0 = (int)y0f, x0 = (int)x0f;
            int y1 = (int)ceilf(cy), x1 = (int)ceilf(cx);
            float ty = cy - y0f, tx = cx - x0f;
            float vlt = xs[(y0 + 1) * 30 + x0 + 1], vrt = xs[(y0 + 1) * 30 + x1 + 1];
            float vlb = xs[(y1 + 1) * 30 + x0 + 1], vrb = xs[(y1 + 1) * 30 + x1 + 1];
            float vt = vlt + (vrt - vlt) * tx;
            float vb = vlb + (vrb - vlb) * tx;
            img2bf[(h + 2) * 36 + (w + 2)] = __float2bfloat16(vt + (vb - vt) * ty);
            h += 9; w += 4;
            if (w >= 28) { w -= 28; h += 1; }
        }
    }
    __syncthreads();

    int wv_ = t >> 6, li = t & 63;
    int lx = li & 15, lg = li >> 4;

    // ---- phase 2: conv1 via MFMA (no B-masking; A zero-padded) -> imgbI ----
    {
        const bf16x8* wc1v = (const bf16x8*)wqc1;
        bf16x8 af1 = wc1v[lx * 4 + lg];
        float b4[4];
#pragma unroll
        for (int r = 0; r < 4; ++r) b4[r] = conv1_b[lg * 4 + r];
        int toff[8];
#pragma unroll
        for (int j = 0; j < 8; ++j) {
            int tt = 8 * lg + j;
            int dyq = tt / 5, dxq = tt - 5 * dyq;
            toff[j] = (tt < 25) ? (dyq * 36 + dxq) : 0;
        }
        int ypstart = (wv_ < 2) ? wv_ * 4 : 8 + (wv_ - 2) * 3;
        int ypcnt = (wv_ < 2) ? 4 : 3;
        const unsigned short* ib28 = (const unsigned short*)img2bf;
        for (int u = 0; u < 4; ++u) {
            if (u < ypcnt) {
                int yp = ypstart + u;
#pragma unroll
                for (int xh = 0; xh < 2; ++xh) {
                    int xp = xh * 16 + lx;
                    f32x4 a0 = (f32x4){0.f, 0.f, 0.f, 0.f};
                    f32x4 a1 = (f32x4){0.f, 0.f, 0.f, 0.f};
#pragma unroll
                    for (int yy = 0; yy < 2; ++yy) {
                        int base16 = (2 * yp + yy) * 36 + xp;
                        unsigned short uu[8];
#pragma unroll
                        for (int j = 0; j < 8; ++j)
                            uu[j] = ib28[base16 + toff[j]];
                        bf16x8 bq = {(short)uu[0], (short)uu[1], (short)uu[2], (short)uu[3],
                                     (short)uu[4], (short)uu[5], (short)uu[6], (short)uu[7]};
                        if (yy == 0)
                            a0 = __builtin_amdgcn_mfma_f32_16x16x32_bf16(af1, bq, a0, 0, 0, 0);
                        else
                            a1 = __builtin_amdgcn_mfma_f32_16x16x32_bf16(af1, bq, a1, 0, 0, 0);
                    }
#pragma unroll
                    for (int r = 0; r < 4; ++r) {
                        float v = fmaxf(fmaxf(a0[r], a1[r]) + b4[r], 0.f);
                        float p = __shfl_xor(v, 1);
                        float m = fmaxf(v, p);
                        if (((xp & 1) == 0) && xp < 28) {
                            int oc = lg * 4 + r;
                            imgbI[(yp + 1) * 256 + ((xp >> 1) + 1) * 16 + oc] = __float2bfloat16(m);
                        }
                    }
                }
            }
        }
    }
    __syncthreads();

    int och = wv_ & 1, yh = wv_ >> 1;
    int nrows = yh ? 6 : 8;
    int aidx = (och * 16 + lx) * 4 + lg;

    // ---- phase A: offset conv via MFMA shift-GEMM (streamed A) -> offbuf ----
    {
        const bf16x8* wA = (const bf16x8*)wqo;
        bf16x8 afc = wA[aidx];
        int slA = lg >> 1, icsel = lg & 1;
        f32x4 acc[8];
#pragma unroll
        for (int y = 0; y < 8; ++y) acc[y] = (f32x4){0.f, 0.f, 0.f, 0.f};
        const bf16x8* ib = (const bf16x8*)imgbI;
        __builtin_amdgcn_s_setprio(1);
#pragma unroll
        for (int sp = 0; sp < 5; ++sp) {
            bf16x8 afn;
            if (sp < 4) afn = wA[(sp + 1) * 128 + aidx];
            int s0 = 2 * sp + slA;
            int dy = s0 / 3, dx = s0 % 3;
            if (s0 >= 9) { dy = 0; dx = 0; }
            int base = dy * 32 + (lx + dx) * 2 + icsel;
#pragma unroll
            for (int y = 0; y < 8; ++y) {
                if (y < nrows) {
                    bf16x8 bfr = ib[base + (yh * 8 + y) * 32];
                    acc[y] = __builtin_amdgcn_mfma_f32_16x16x32_bf16(afc, bfr, acc[y], 0, 0, 0);
                }
            }
            afc = afn;
        }
        __builtin_amdgcn_s_setprio(0);
        if (lx < 14) {
#pragma unroll
            for (int y = 0; y < 8; ++y) {
                if (y < nrows) {
                    int yy = yh * 8 + y;
#pragma unroll
                    for (int r = 0; r < 4; ++r) {
                        int oc = och * 16 + lg * 4 + r;
                        offbuf[oc * 196 + yy * 14 + lx] = (_Float16)acc[y][r];
                    }
                }
            }
        }
    }
    __syncthreads();

    // ---- phase B: remap + bilinear, register-staged so img2b overlays offbuf ----
    {
        float vres[13];
        {
            int c = t & 15;
            int rem0 = t >> 4;
            int h = (rem0 >= 14) ? 1 : 0;
            int w = rem0 - 14 * h;
#pragma unroll
            for (int u = 0; u < 13; ++u) {
                if (h < 14) {
                    int pidx = c * 196 + h * 14 + w;
                    unsigned int pr = ((const unsigned int*)offbuf)[pidx];
                    unsigned short lo16 = (unsigned short)(pr & 0xFFFFu);
                    unsigned short hi16 = (unsigned short)(pr >> 16);
                    float offy = (float)(*(const _Float16*)&lo16);
                    float offx = (float)(*(const _Float16*)&hi16);
                    float cy = fminf(fmaxf((float)h + offy, 0.f), 13.f);
                    float cx = fminf(fmaxf((float)w + offx, 0.f), 13.f);
                    float y0f = floorf(cy), x0f = floorf(cx);
                    int y0 = (int)y0f, x0 = (int)x0f;
                    int y1 = (int)ceilf(cy), x1 = (int)ceilf(cx);
                    float ty = cy - y0f, tx = cx - x0f;
                    float vlt = __bfloat162float(imgbI[(y0 + 1) * 256 + (x0 + 1) * 16 + c]);
                    float vrt = __bfloat162float(imgbI[(y0 + 1) * 256 + (x1 + 1) * 16 + c]);
                    float vlb = __bfloat162float(imgbI[(y1 + 1) * 256 + (x0 + 1) * 16 + c]);
                    float vrb = __bfloat162float(imgbI[(y1 + 1) * 256 + (x1 + 1) * 16 + c]);
                    float vt = vlt + (vrt - vlt) * tx;
                    float vb = vlb + (vrb - vlb) * tx;
                    vres[u] = vt + (vb - vt) * ty;
                }
                h += 1; w += 2;
                if (w >= 14) { w -= 14; h += 1; }
            }
        }
        __syncthreads();  // all offbuf/imgbI reads done; s5i becomes img2b
        // zero pad cells of img2b (interior fully overwritten below)
        for (int p = t; p < 360; p += 256) {
            int r = p / 20, cc = p % 20;
            if (r < 2 || r > 15 || cc < 2 || cc > 15) {
                unsigned int* dst = (unsigned int*)&img2b[p * 16];
#pragma unroll
                for (int q = 0; q < 8; ++q) dst[q] = 0u;
            }
        }
        {
            int c = t & 15;
            int rem0 = t >> 4;
            int h = (rem0 >= 14) ? 1 : 0;
            int w = rem0 - 14 * h;
#pragma unroll
            for (int u = 0; u < 13; ++u) {
                if (h < 14)
                    img2b[((h + 2) * 20 + (w + 2)) * 16 + c] = __float2bfloat16(vres[u]);
                h += 1; w += 2;
                if (w >= 14) { w -= 14; h += 1; }
            }
        }
    }
    __syncthreads();

    // ---- phase C: conv2 MFMA shift-GEMM (streamed A) + bias+relu+pool -> pl ----
    {
        const bf16x8* wB = (const bf16x8*)wq2;
        bf16x8 afc = wB[aidx];
        int sl = lg >> 1, icg = lg & 1;
        float bias_r[4];
#pragma unroll
        for (int r = 0; r < 4; ++r) bias_r[r] = conv2_b[och * 16 + lg * 4 + r];
        f32x4 acc[8];
#pragma unroll
        for (int y = 0; y < 8; ++y) acc[y] = (f32x4){0.f, 0.f, 0.f, 0.f};
        const bf16x8* ib2 = (const bf16x8*)img2b;
        __builtin_amdgcn_s_setprio(1);
#pragma unroll
        for (int sp = 0; sp < 13; ++sp) {
            bf16x8 afn;
            if (sp < 12) afn = wB[(sp + 1) * 128 + aidx];
            int s0 = 2 * sp + sl;
            int dy = s0 / 5, dx = s0 % 5;
            if (s0 >= 25) { dy = 0; dx = 0; }
            int base = (lx + dx) * 2 + icg;
#pragma unroll
            for (int y = 0; y < 8; ++y) {
                if (y < nrows) {
                    bf16x8 bfr = ib2[base + (yh * 8 + y + dy) * 40];
                    acc[y] = __builtin_amdgcn_mfma_f32_16x16x32_bf16(afc, bfr, acc[y], 0, 0, 0);
                }
            }
            afc = afn;
        }
        __builtin_amdgcn_s_setprio(0);
        // pool writes go to pl (overlays imgbI, dead since phase B's barrier)
        int npool = yh ? 3 : 4;
#pragma unroll
        for (int u = 0; u < 4; ++u) {
            if (u < npool) {
                int i = yh * 4 + u;
#pragma unroll
                for (int r = 0; r < 4; ++r) {
                    int oc = och * 16 + lg * 4 + r;
                    float v = fmaxf(fmaxf(acc[2 * u][r], acc[2 * u + 1][r]) + bias_r[r], 0.f);
                    float p = __shfl_xor(v, 1);
                    float m = fmaxf(v, p);
                    if (((lx & 1) == 0) && lx < 14)
                        pl[oc * 49 + i * 7 + (lx >> 1)] = m;
                }
            }
        }
    }
    __syncthreads();

    // ---- phase E: FC 1568->10 (float4 loads) ----
    float facc[10];
#pragma unroll
    for (int o = 0; o < 10; ++o) facc[o] = 0.f;
#pragma unroll
    for (int it = 0; it < 2; ++it) {
        int k = t * 4 + it * 1024;
        if (k < 1568) {
            float4 v = *(const float4*)&pl[k];
#pragma unroll
            for (int o = 0; o < 10; ++o) {
                float4 w4 = *(const float4*)&fc_w[o * 1568 + k];
                facc[o] += v.x * w4.x + v.y * w4.y + v.z * w4.z + v.w * w4.w;
            }
        }
    }
#pragma unroll
    for (int o = 0; o < 10; ++o) {
        float s = facc[o];
#pragma unroll
        for (int m = 32; m > 0; m >>= 1) s += __shfl_xor(s, m);
        if (li == 0) wredp[o * 4 + wv_] = s;
    }
    __syncthreads();
    if (t < 10)
        out[b * 10 + t] = fc_b[t] + wredp[t * 4] + wredp[t * 4 + 1] + wredp[t * 4 + 2] + wredp[t * 4 + 3];
}

extern "C" void kernel_launch(void* const* d_in, const int* in_sizes, int n_in,
                              void* d_out, int out_size, void* d_ws, size_t ws_size,
                              hipStream_t stream) {
    const float* x       = (const float*)d_in[0];
    const float* off1_w  = (const float*)d_in[1];
    const float* conv1_w = (const float*)d_in[2];
    const float* conv1_b = (const float*)d_in[3];
    const float* off2_w  = (const float*)d_in[4];
    const float* conv2_w = (const float*)d_in[5];
    const float* conv2_b = (const float*)d_in[6];
    const float* fc_w    = (const float*)d_in[7];
    const float* fc_b    = (const float*)d_in[8];
    float* out = (float*)d_out;

    char* ws = (char*)d_ws;
    __hip_bfloat16* wqo  = (__hip_bfloat16*)ws;             // 5120 bf16  = 10240 B
    __hip_bfloat16* wq2  = (__hip_bfloat16*)(ws + 10240);   // 13312 bf16 = 26624 B
    __hip_bfloat16* wqc1 = (__hip_bfloat16*)(ws + 36864);   // 512 bf16   = 1024 B

    k_prep<<<74, 256, 0, stream>>>(off2_w, conv2_w, conv1_w, wqo, wq2, wqc1);
    k_net<<<B_IMG / 2, 512, 0, stream>>>(x, off1_w, wqc1, conv1_b, wqo, wq2,
                                         conv2_b, fc_w, fc_b, out);
}

// Round 19
// 56.845 us; speedup vs baseline: 1.0481x; 1.0481x over previous
//
#include <hip/hip_runtime.h>
#include <hip/hip_bf16.h>

// Fully-fused deform-conv MNIST net. B=2048, one block per image, 256 thr.
// LDS = 32256 B. All three convs on MFMA. A-fragments streamed from L2.
// r19 = r17 + barrier pruning: single phase-0 barrier (disjoint writes),
//       mid-phase-C barrier deleted (pl overlay safe after phase-B barrier).
//   s5    : xs|img2bf (ph0-1) -> offbuf (phA-B) -> pl+wred (phC-E)
//   imgb  : bf16 ch-last h1 [16][16][16] (ph2-B)
//   img2b : bf16 ch-last d2 [18][20][16] (phB-C)

#define B_IMG 2048

typedef short bf16x8 __attribute__((ext_vector_type(8)));
typedef float f32x4 __attribute__((ext_vector_type(4)));

// wqo  [5][32][32]  : off2_w (32,16,3,3) -> k=sl*16+ic, s=2*sp+sl, s>=9 zero
// wq2  [13][32][32] : conv2_w (32,16,5,5) -> s>=25 zero
// wqc1 [16][32]     : conv1_w (16,1,5,5)  -> k=tap, k>=25 zero
__global__ __launch_bounds__(256) void k_prep(const float* __restrict__ w_off2,
                                              const float* __restrict__ w_c2,
                                              const float* __restrict__ w_c1,
                                              __hip_bfloat16* __restrict__ wqo,
                                              __hip_bfloat16* __restrict__ wq2,
                                              __hip_bfloat16* __restrict__ wqc1) {
    int e = blockIdx.x * 256 + threadIdx.x;
    if (e < 5120) {
        int sp = e >> 10, rem = e & 1023, oc = rem >> 5, k = rem & 31;
        int sl = k >> 4, ic = k & 15, s = 2 * sp + sl;
        wqo[e] = __float2bfloat16(s < 9 ? w_off2[(oc * 16 + ic) * 9 + s] : 0.f);
    } else if (e < 18432) {
        int e2 = e - 5120;
        int sp = e2 >> 10, rem = e2 & 1023, oc = rem >> 5, k = rem & 31;
        int sl = k >> 4, ic = k & 15, s = 2 * sp + sl;
        wq2[e2] = __float2bfloat16(s < 25 ? w_c2[(oc * 16 + ic) * 25 + s] : 0.f);
    } else if (e < 18944) {
        int e3 = e - 18432;
        int oc = e3 >> 5, k = e3 & 31;
        wqc1[e3] = __float2bfloat16(k < 25 ? w_c1[oc * 25 + k] : 0.f);
    }
}

__global__ __launch_bounds__(256, 4) void k_net(const float* __restrict__ x,        // (B,1,28,28)
                                                const float* __restrict__ off1_w,   // (2,1,3,3)
                                                const __hip_bfloat16* __restrict__ wqc1,
                                                const float* __restrict__ conv1_b,  // (16)
                                                const __hip_bfloat16* __restrict__ wqo,
                                                const __hip_bfloat16* __restrict__ wq2,
                                                const float* __restrict__ conv2_b,  // (32)
                                                const float* __restrict__ fc_w,     // (10,1568)
                                                const float* __restrict__ fc_b,     // (10)
                                                float* __restrict__ out) {          // (B,10)
    __shared__ __align__(16) char s5[12544];                      // multi-use scratch
    __shared__ __align__(16) __hip_bfloat16 imgb[16 * 16 * 16];   // 8192 B
    __shared__ __align__(16) __hip_bfloat16 img2b[18 * 20 * 16];  // 11520 B

    float* xs = (float*)s5;                       // [30][30] pad1, 3600 B
    __hip_bfloat16* img2bf = (__hip_bfloat16*)(s5 + 3600);  // [32][36] pad2 bf16, 2304 B
    _Float16* offbuf = (_Float16*)s5;             // phase A-B, 12544 B
    float* pl    = (float*)s5;                    // phase C-E, 6272 B (pooled 32x7x7)
    float* wredp = (float*)(s5 + 6272);           // phase E, 160 B

    int b = blockIdx.x, t = threadIdx.x;

    // ---- phase 0: prefetch x to regs, zero pads, stage interior — ONE barrier ----
    float xreg[4];
#pragma unroll
    for (int j = 0; j < 4; ++j) {
        int i = t + j * 256;
        xreg[j] = (i < 784) ? x[b * 784 + i] : 0.f;  // HBM loads issued early
    }
    // xs pad ring only (116 cells; interior written from xreg below — disjoint)
    if (t < 116) {
        int row, col;
        if (t < 30) { row = 0; col = t; }
        else if (t < 60) { row = 29; col = t - 30; }
        else { int q = t - 60; row = 1 + (q >> 1); col = (q & 1) * 29; }
        xs[row * 30 + col] = 0.f;
    }
    for (int i = t; i < 576; i += 256) ((unsigned int*)img2bf)[i] = 0u;
    // imgb: interior fully overwritten by phase 2 -> zero only pad cells (480 words)
    for (int i = t; i < 480; i += 256) {
        int word = i & 7;
        int cell = i >> 3;  // 0..59
        int row, col;
        if (cell < 16) { row = 0; col = cell; }
        else if (cell < 32) { row = 15; col = cell - 16; }
        else { int q = cell - 32; row = 1 + (q >> 1); col = (q & 1) * 15; }
        ((unsigned int*)imgb)[(row * 16 + col) * 8 + word] = 0u;
    }
    // img2b: interior fully overwritten by phase B -> zero only pad cells
    for (int p = t; p < 360; p += 256) {
        int r = p / 20, cc = p % 20;
        if (r < 2 || r > 15 || cc < 2 || cc > 15) {
            unsigned int* dst = (unsigned int*)&img2b[p * 16];
#pragma unroll
            for (int q = 0; q < 8; ++q) dst[q] = 0u;
        }
    }
    // xs interior from xreg (disjoint from pad ring writes — same phase OK)
#pragma unroll
    for (int j = 0; j < 4; ++j) {
        int i = t + j * 256;
        if (i < 784) xs[(i / 28 + 1) * 30 + (i % 28) + 1] = xreg[j];
    }
    __syncthreads();

    // ---- phase 1: deform1 -> img2bf (bf16, pad2, 36-wide); division-free ----
    {
        int h = t / 28, w = t % 28;  // one div; then incremental
        for (int p = t; p < 784; p += 256) {
            int c = (h >= 14) ? 1 : 0;
            int hp = h - 14 * c;
            const float* wo = off1_w + c * 9;
            float off[2];
#pragma unroll
            for (int k = 0; k < 2; ++k) {
                int e = 2 * w + k;
                int wrap = (e >= 28) ? 1 : 0;
                int hh = 2 * hp + wrap;
                int ww = e - 28 * wrap;
                float s = 0.f;
#pragma unroll
                for (int dy = 0; dy < 3; ++dy)
#pragma unroll
                    for (int dx = 0; dx < 3; ++dx)
                        s += wo[dy * 3 + dx] * xs[(hh + dy) * 30 + ww + dx];
                off[k] = s;
            }
            float cy = fminf(fmaxf((float)h + off[0], 0.f), 27.f);
            float cx = fminf(fmaxf((float)w + off[1], 0.f), 27.f);
            float y0f = floorf(cy), x0f = floorf(cx);
            int y0 = (int)y0f, x0 = (int)x0f;
            int y1 = (int)ceilf(cy), x1 = (int)ceilf(cx);
            float ty = cy - y0f, tx = cx - x0f;
            float vlt = xs[(y0 + 1) * 30 + x0 + 1], vrt = xs[(y0 + 1) * 30 + x1 + 1];
            float vlb = xs[(y1 + 1) * 30 + x0 + 1], vrb = xs[(y1 + 1) * 30 + x1 + 1];
            float vt = vlt + (vrt - vlt) * tx;
            float vb = vlb + (vrb - vlb) * tx;
            img2bf[(h + 2) * 36 + (w + 2)] = __float2bfloat16(vt + (vb - vt) * ty);
            h += 9; w += 4;
            if (w >= 28) { w -= 28; h += 1; }
        }
    }
    __syncthreads();

    int wv_ = t >> 6, li = t & 63;
    int lx = li & 15, lg = li >> 4;

    // ---- phase 2: conv1 via MFMA (no B-masking; A zero-padded) -> imgb ----
    {
        const bf16x8* wc1v = (const bf16x8*)wqc1;
        bf16x8 af1 = wc1v[lx * 4 + lg];  // A: row=oc=lx, k-slice=lg*8
        float b4[4];
#pragma unroll
        for (int r = 0; r < 4; ++r) b4[r] = conv1_b[lg * 4 + r];
        int toff[8];
#pragma unroll
        for (int j = 0; j < 8; ++j) {
            int tt = 8 * lg + j;
            int dyq = tt / 5, dxq = tt - 5 * dyq;
            toff[j] = (tt < 25) ? (dyq * 36 + dxq) : 0;
        }
        int ypstart = (wv_ < 2) ? wv_ * 4 : 8 + (wv_ - 2) * 3;
        int ypcnt = (wv_ < 2) ? 4 : 3;
        const unsigned short* ib28 = (const unsigned short*)img2bf;
        for (int u = 0; u < 4; ++u) {
            if (u < ypcnt) {
                int yp = ypstart + u;
#pragma unroll
                for (int xh = 0; xh < 2; ++xh) {
                    int xp = xh * 16 + lx;  // conv position x (B col = lx)
                    f32x4 a0 = (f32x4){0.f, 0.f, 0.f, 0.f};
                    f32x4 a1 = (f32x4){0.f, 0.f, 0.f, 0.f};
#pragma unroll
                    for (int yy = 0; yy < 2; ++yy) {
                        int base16 = (2 * yp + yy) * 36 + xp;
                        unsigned short uu[8];
#pragma unroll
                        for (int j = 0; j < 8; ++j)
                            uu[j] = ib28[base16 + toff[j]];
                        bf16x8 bq = {(short)uu[0], (short)uu[1], (short)uu[2], (short)uu[3],
                                     (short)uu[4], (short)uu[5], (short)uu[6], (short)uu[7]};
                        if (yy == 0)
                            a0 = __builtin_amdgcn_mfma_f32_16x16x32_bf16(af1, bq, a0, 0, 0, 0);
                        else
                            a1 = __builtin_amdgcn_mfma_f32_16x16x32_bf16(af1, bq, a1, 0, 0, 0);
                    }
#pragma unroll
                    for (int r = 0; r < 4; ++r) {
                        float v = fmaxf(fmaxf(a0[r], a1[r]) + b4[r], 0.f);
                        float p = __shfl_xor(v, 1);
                        float m = fmaxf(v, p);
                        if (((xp & 1) == 0) && xp < 28) {
                            int oc = lg * 4 + r;
                            imgb[(yp + 1) * 256 + ((xp >> 1) + 1) * 16 + oc] = __float2bfloat16(m);
                        }
                    }
                }
            }
        }
    }
    __syncthreads();

    int och = wv_ & 1, yh = wv_ >> 1;   // wave -> (oc half, row half)
    int nrows = yh ? 6 : 8;             // rows gy = yh*8 + y
    int aidx = (och * 16 + lx) * 4 + lg;  // A-fragment index within one sp-slab

    // ---- phase A: offset conv (32,14,14) via MFMA shift-GEMM (streamed A) ----
    {
        const bf16x8* wA = (const bf16x8*)wqo;
        bf16x8 afc = wA[aidx];
        int slA = lg >> 1, icsel = lg & 1;
        f32x4 acc[8];
#pragma unroll
        for (int y = 0; y < 8; ++y) acc[y] = (f32x4){0.f, 0.f, 0.f, 0.f};
        const bf16x8* ib = (const bf16x8*)imgb;
        __builtin_amdgcn_s_setprio(1);
#pragma unroll
        for (int sp = 0; sp < 5; ++sp) {
            bf16x8 afn;
            if (sp < 4) afn = wA[(sp + 1) * 128 + aidx];  // prefetch next slab
            int s0 = 2 * sp + slA;
            int dy = s0 / 3, dx = s0 % 3;
            if (s0 >= 9) { dy = 0; dx = 0; }  // zero-weight pad step
            int base = dy * 32 + (lx + dx) * 2 + icsel;
#pragma unroll
            for (int y = 0; y < 8; ++y) {
                if (y < nrows) {
                    bf16x8 bfr = ib[base + (yh * 8 + y) * 32];
                    acc[y] = __builtin_amdgcn_mfma_f32_16x16x32_bf16(afc, bfr, acc[y], 0, 0, 0);
                }
            }
            afc = afn;
        }
        __builtin_amdgcn_s_setprio(0);
        if (lx < 14) {
#pragma unroll
            for (int y = 0; y < 8; ++y) {
                if (y < nrows) {
                    int yy = yh * 8 + y;
#pragma unroll
                    for (int r = 0; r < 4; ++r) {
                        int oc = och * 16 + lg * 4 + r;
                        offbuf[oc * 196 + yy * 14 + lx] = (_Float16)acc[y][r];
                    }
                }
            }
        }
    }
    __syncthreads();

    // ---- phase B: raw-reshape remap + bilinear -> img2b (c-inner, incremental h,w) ----
    {
        int c = t & 15;
        int rem0 = t >> 4;              // 0..15
        int h = (rem0 >= 14) ? 1 : 0;
        int w = rem0 - 14 * h;
#pragma unroll
        for (int u = 0; u < 13; ++u) {
            if (h < 14) {
                int pidx = c * 196 + h * 14 + w;
                unsigned int pr = ((const unsigned int*)offbuf)[pidx];
                unsigned short lo16 = (unsigned short)(pr & 0xFFFFu);
                unsigned short hi16 = (unsigned short)(pr >> 16);
                float offy = (float)(*(const _Float16*)&lo16);
                float offx = (float)(*(const _Float16*)&hi16);
                float cy = fminf(fmaxf((float)h + offy, 0.f), 13.f);
                float cx = fminf(fmaxf((float)w + offx, 0.f), 13.f);
                float y0f = floorf(cy), x0f = floorf(cx);
                int y0 = (int)y0f, x0 = (int)x0f;
                int y1 = (int)ceilf(cy), x1 = (int)ceilf(cx);
                float ty = cy - y0f, tx = cx - x0f;
                float vlt = __bfloat162float(imgb[(y0 + 1) * 256 + (x0 + 1) * 16 + c]);
                float vrt = __bfloat162float(imgb[(y0 + 1) * 256 + (x1 + 1) * 16 + c]);
                float vlb = __bfloat162float(imgb[(y1 + 1) * 256 + (x0 + 1) * 16 + c]);
                float vrb = __bfloat162float(imgb[(y1 + 1) * 256 + (x1 + 1) * 16 + c]);
                float vt = vlt + (vrt - vlt) * tx;
                float vb = vlb + (vrb - vlb) * tx;
                img2b[((h + 2) * 20 + (w + 2)) * 16 + c] = __float2bfloat16(vt + (vb - vt) * ty);
            }
            h += 1; w += 2;
            if (w >= 14) { w -= 14; h += 1; }
        }
    }
    __syncthreads();

    // ---- phase C: conv2 MFMA shift-GEMM (streamed A) + bias + relu + pool -> pl ----
    // NOTE: no mid-phase barrier — offbuf's (s5) last reads ended at the
    // phase-B barrier, so pool writes to pl (overlaying s5) are race-free.
    {
        const bf16x8* wB = (const bf16x8*)wq2;
        bf16x8 afc = wB[aidx];
        int sl = lg >> 1, icg = lg & 1;
        float bias_r[4];
#pragma unroll
        for (int r = 0; r < 4; ++r) bias_r[r] = conv2_b[och * 16 + lg * 4 + r];
        f32x4 acc[8];
#pragma unroll
        for (int y = 0; y < 8; ++y) acc[y] = (f32x4){0.f, 0.f, 0.f, 0.f};
        const bf16x8* ib2 = (const bf16x8*)img2b;
        __builtin_amdgcn_s_setprio(1);
#pragma unroll
        for (int sp = 0; sp < 13; ++sp) {
            bf16x8 afn;
            if (sp < 12) afn = wB[(sp + 1) * 128 + aidx];  // prefetch next slab
            int s0 = 2 * sp + sl;
            int dy = s0 / 5, dx = s0 % 5;
            if (s0 >= 25) { dy = 0; dx = 0; }
            int base = (lx + dx) * 2 + icg;
#pragma unroll
            for (int y = 0; y < 8; ++y) {
                if (y < nrows) {
                    bf16x8 bfr = ib2[base + (yh * 8 + y + dy) * 40];
                    acc[y] = __builtin_amdgcn_mfma_f32_16x16x32_bf16(afc, bfr, acc[y], 0, 0, 0);
                }
            }
            afc = afn;
        }
        __builtin_amdgcn_s_setprio(0);
        int npool = yh ? 3 : 4;
#pragma unroll
        for (int u = 0; u < 4; ++u) {
            if (u < npool) {
                int i = yh * 4 + u;
#pragma unroll
                for (int r = 0; r < 4; ++r) {
                    int oc = och * 16 + lg * 4 + r;
                    float v = fmaxf(fmaxf(acc[2 * u][r], acc[2 * u + 1][r]) + bias_r[r], 0.f);
                    float p = __shfl_xor(v, 1);
                    float m = fmaxf(v, p);
                    if (((lx & 1) == 0) && lx < 14)
                        pl[oc * 49 + i * 7 + (lx >> 1)] = m;
                }
            }
        }
    }
    __syncthreads();

    // ---- phase E: FC 1568->10 (float4 loads) ----
    float facc[10];
#pragma unroll
    for (int o = 0; o < 10; ++o) facc[o] = 0.f;
#pragma unroll
    for (int it = 0; it < 2; ++it) {
        int k = t * 4 + it * 1024;
        if (k < 1568) {
            float4 v = *(const float4*)&pl[k];
#pragma unroll
            for (int o = 0; o < 10; ++o) {
                float4 w4 = *(const float4*)&fc_w[o * 1568 + k];
                facc[o] += v.x * w4.x + v.y * w4.y + v.z * w4.z + v.w * w4.w;
            }
        }
    }
#pragma unroll
    for (int o = 0; o < 10; ++o) {
        float s = facc[o];
#pragma unroll
        for (int m = 32; m > 0; m >>= 1) s += __shfl_xor(s, m);
        if (li == 0) wredp[o * 4 + wv_] = s;
    }
    __syncthreads();
    if (t < 10)
        out[b * 10 + t] = fc_b[t] + wredp[t * 4] + wredp[t * 4 + 1] + wredp[t * 4 + 2] + wredp[t * 4 + 3];
}

extern "C" void kernel_launch(void* const* d_in, const int* in_sizes, int n_in,
                              void* d_out, int out_size, void* d_ws, size_t ws_size,
                              hipStream_t stream) {
    const float* x       = (const float*)d_in[0];
    const float* off1_w  = (const float*)d_in[1];
    const float* conv1_w = (const float*)d_in[2];
    const float* conv1_b = (const float*)d_in[3];
    const float* off2_w  = (const float*)d_in[4];
    const float* conv2_w = (const float*)d_in[5];
    const float* conv2_b = (const float*)d_in[6];
    const float* fc_w    = (const float*)d_in[7];
    const float* fc_b    = (const float*)d_in[8];
    float* out = (float*)d_out;

    char* ws = (char*)d_ws;
    __hip_bfloat16* wqo  = (__hip_bfloat16*)ws;             // 5120 bf16  = 10240 B
    __hip_bfloat16* wq2  = (__hip_bfloat16*)(ws + 10240);   // 13312 bf16 = 26624 B
    __hip_bfloat16* wqc1 = (__hip_bfloat16*)(ws + 36864);   // 512 bf16   = 1024 B

    k_prep<<<74, 256, 0, stream>>>(off2_w, conv2_w, conv1_w, wqo, wq2, wqc1);
    k_net<<<B_IMG, 256, 0, stream>>>(x, off1_w, wqc1, conv1_b, wqo, wq2,
                                     conv2_b, fc_w, fc_b, out);
}